// Round 7
// baseline (252.927 us; speedup 1.0000x reference)
//
#include <hip/hip_runtime.h>
#include <math.h>

#define NMOL  1024
#define N     128          // atoms per molecule (Schur-reduced SPD system size)
#define NELEM 10
#define BLOCK 256
#define PW    8            // panel width
#define NPAN  16           // 128 / 8
#define PSTR  12           // panel-column buffer row stride (floats)
#define USTR  132          // U-panel row stride (cols 0..129: 128=rhsY, 129=rhsZ)

typedef __attribute__((ext_vector_type(4))) float f4;

// wave w (=tid>>6) owns column chunks [8w, 8w+8) (32 cols).
// lane l owns rows r0=2l, r1=2l+1 of those columns: Ar0[8], Ar1[8] (f4 each).

__global__ __launch_bounds__(BLOCK, 4) void ceq_solve_kernel(
    const float* __restrict__ eneg,
    const float* __restrict__ positions,
    const float* __restrict__ node_attrs,
    const float* __restrict__ hardness,
    const float* __restrict__ total_charge,
    const int*   __restrict__ atomic_numbers,
    float* __restrict__ out)
{
    __shared__ __align__(16) float P[N * PSTR];        // staged panel columns (128 x 8)
    __shared__ __align__(16) float Up[PW * USTR];      // staged panel rows (8 x 130)
    __shared__ __align__(16) float Ublk[NPAN][PW][PW]; // per-panel 8x8 diag blocks
    __shared__ float rhsY[N], rhsZ[N];
    __shared__ float sxY[N], sxZ[N];
    __shared__ float px[N], py[N], pz[N], sg[N], dgv[N];
    __shared__ float lamS;

    const int m    = blockIdx.x;
    const int tid  = threadIdx.x;
    const int lane = tid & 63;
    const int wid  = tid >> 6;
    const int r0   = 2 * lane;
    const int r1   = r0 + 1;
    const int col0 = 32 * wid;
    const int base = m * N;

    // ---- per-atom precompute ----
    if (tid < N) {
        const int i = tid;
        const int Z = atomic_numbers[base + i];
        const float rad = 0.3f + 0.02f * (float)Z;
        sg[i] = rad * rad;
        const float* na = node_attrs + (size_t)(base + i) * NELEM;
        float best = na[0]; int bi = 0;
        #pragma unroll
        for (int e = 1; e < NELEM; ++e) {
            float v = na[e];
            if (v > best) { best = v; bi = e; }     // first-max = jnp.argmax
        }
        dgv[i] = hardness[bi] + 0.5641895835477563f / rad;  // h + 1/(sqrt(pi) r)
        const float* p = positions + (size_t)(base + i) * 3;
        px[i] = p[0]; py[i] = p[1]; pz[i] = p[2];
        rhsY[i] = -eneg[base + i];   // A y = b
        rhsZ[i] = 1.0f;              // A z = 1
    }
    __syncthreads();

    // ---- fill register tiles: rows r0,r1 x cols [col0, col0+32), one row at a time ----
    f4 Ar0[8], Ar1[8];
    {
        const float x0 = px[r0], y0 = py[r0], z0 = pz[r0], s0 = sg[r0], d0 = dgv[r0];
        #pragma unroll
        for (int c = 0; c < 8; ++c) {
            f4 v0;
            #pragma unroll
            for (int e = 0; e < 4; ++e) {
                const int j = col0 + 4 * c + e;
                float a0;
                if (j == r0) a0 = d0;
                else {
                    const float dx = x0 - px[j], dy = y0 - py[j], dz = z0 - pz[j];
                    const float d = sqrtf(dx * dx + dy * dy + dz * dz);
                    a0 = erff(d / (1.4142135623730951f * sqrtf(s0 + sg[j]))) / d;
                }
                ((float*)&v0)[e] = a0;
            }
            Ar0[c] = v0;
        }
        const float x1 = px[r1], y1 = py[r1], z1 = pz[r1], s1 = sg[r1], d1 = dgv[r1];
        #pragma unroll
        for (int c = 0; c < 8; ++c) {
            f4 v1;
            #pragma unroll
            for (int e = 0; e < 4; ++e) {
                const int j = col0 + 4 * c + e;
                float a1;
                if (j == r1) a1 = d1;
                else {
                    const float dx = x1 - px[j], dy = y1 - py[j], dz = z1 - pz[j];
                    const float d = sqrtf(dx * dx + dy * dy + dz * dz);
                    a1 = erff(d / (1.4142135623730951f * sqrtf(s1 + sg[j]))) / d;
                }
                ((float*)&v1)[e] = a1;
            }
            Ar1[c] = v1;
        }
    }

    // ================= blocked unpivoted LU, A register-resident =================
    for (int p = 0; p < NPAN; ++p) {
        const int k0   = PW * p;
        const int gclo = 2 * p + 2;          // first trailing chunk (global)
        const int wp   = p >> 2;             // wave holding panel columns

        // ---- stage panel columns (rows >= k0) -> P ----
        if (wid == wp && lane >= 4 * p) {
            f4 a00, a01, a10, a11;
            switch (p & 3) {
                case 0:  a00 = Ar0[0]; a01 = Ar0[1]; a10 = Ar1[0]; a11 = Ar1[1]; break;
                case 1:  a00 = Ar0[2]; a01 = Ar0[3]; a10 = Ar1[2]; a11 = Ar1[3]; break;
                case 2:  a00 = Ar0[4]; a01 = Ar0[5]; a10 = Ar1[4]; a11 = Ar1[5]; break;
                default: a00 = Ar0[6]; a01 = Ar0[7]; a10 = Ar1[6]; a11 = Ar1[7]; break;
            }
            *(f4*)&P[r0 * PSTR + 0] = a00; *(f4*)&P[r0 * PSTR + 4] = a01;
            *(f4*)&P[r1 * PSTR + 0] = a10; *(f4*)&P[r1 * PSTR + 4] = a11;
        }
        // ---- stage panel rows (trailing chunks of quarter) -> Up ----
        if (lane >= 4 * p && lane < 4 * p + 4) {
            const int u0 = r0 - k0, u1 = u0 + 1;
            #pragma unroll
            for (int c = 0; c < 8; ++c) {
                const int gc = 8 * wid + c;
                if (gc >= gclo) {
                    *(f4*)&Up[u0 * USTR + 4 * gc] = Ar0[c];
                    *(f4*)&Up[u1 * USTR + 4 * gc] = Ar1[c];
                }
            }
        }
        if (tid < PW) {
            Up[tid * USTR + 128] = rhsY[k0 + tid];
            Up[tid * USTR + 129] = rhsZ[k0 + tid];
        }
        __syncthreads();

        // ---- panel factor: wave 0, rows k0..127, shuffle broadcasts ----
        if (wid == 0) {
            const int i0 = k0 + lane, i1 = i0 + 64;
            const bool v0 = i0 < N, v1 = i1 < N;
            float rg0[PW], rg1[PW];
            if (v0) {
                f4 a = *(const f4*)&P[i0 * PSTR], b = *(const f4*)&P[i0 * PSTR + 4];
                rg0[0]=a.x; rg0[1]=a.y; rg0[2]=a.z; rg0[3]=a.w;
                rg0[4]=b.x; rg0[5]=b.y; rg0[6]=b.z; rg0[7]=b.w;
            } else {
                #pragma unroll
                for (int j = 0; j < PW; ++j) rg0[j] = 0.0f;
            }
            if (v1) {
                f4 a = *(const f4*)&P[i1 * PSTR], b = *(const f4*)&P[i1 * PSTR + 4];
                rg1[0]=a.x; rg1[1]=a.y; rg1[2]=a.z; rg1[3]=a.w;
                rg1[4]=b.x; rg1[5]=b.y; rg1[6]=b.z; rg1[7]=b.w;
            } else {
                #pragma unroll
                for (int j = 0; j < PW; ++j) rg1[j] = 0.0f;
            }
            #pragma unroll
            for (int kk = 0; kk < PW; ++kk) {
                float pr[PW];
                #pragma unroll
                for (int j = kk; j < PW; ++j) pr[j] = __shfl(rg0[j], kk);
                const float dinv = 1.0f / pr[kk];
                if (v0 && i0 > k0 + kk) {
                    const float mult = rg0[kk] * dinv; rg0[kk] = mult;
                    #pragma unroll
                    for (int j = kk + 1; j < PW; ++j) rg0[j] -= mult * pr[j];
                }
                if (v1) {
                    const float mult = rg1[kk] * dinv; rg1[kk] = mult;
                    #pragma unroll
                    for (int j = kk + 1; j < PW; ++j) rg1[j] -= mult * pr[j];
                }
            }
            if (v0) {
                f4 a = { rg0[0], rg0[1], rg0[2], rg0[3] };
                f4 b = { rg0[4], rg0[5], rg0[6], rg0[7] };
                *(f4*)&P[i0 * PSTR] = a; *(f4*)&P[i0 * PSTR + 4] = b;
                if (lane < PW) { *(f4*)&Ublk[p][lane][0] = a; *(f4*)&Ublk[p][lane][4] = b; }
            }
            if (v1) {
                f4 a = { rg1[0], rg1[1], rg1[2], rg1[3] };
                f4 b = { rg1[4], rg1[5], rg1[6], rg1[7] };
                *(f4*)&P[i1 * PSTR] = a; *(f4*)&P[i1 * PSTR + 4] = b;
            }
        }
        __syncthreads();

        // ---- TRSM: L11^-1 over cols k0+8..127 plus rhs cols 128,129 ----
        const int ncols = 122 - k0;
        if (tid < ncols) {
            const int j = k0 + PW + tid;
            float u[PW];
            #pragma unroll
            for (int kk = 0; kk < PW; ++kk) u[kk] = Up[kk * USTR + j];
            #pragma unroll
            for (int kk = 1; kk < PW; ++kk) {
                float acc = u[kk];
                #pragma unroll
                for (int t = 0; t < kk; ++t) acc -= Ublk[p][kk][t] * u[t];
                u[kk] = acc;
            }
            #pragma unroll
            for (int kk = 0; kk < PW; ++kk) Up[kk * USTR + j] = u[kk];
        }
        __syncthreads();

        // ---- owner reload, rhs persist, GEMM (two row passes, low reg pressure) ----
        if (lane >= 4 * p && lane < 4 * p + 4) {     // owners pull TRSM'd U to regs
            const int u0 = r0 - k0, u1 = u0 + 1;
            #pragma unroll
            for (int c = 0; c < 8; ++c) {
                const int gc = 8 * wid + c;
                if (gc >= gclo) {
                    Ar0[c] = *(const f4*)&Up[u0 * USTR + 4 * gc];
                    Ar1[c] = *(const f4*)&Up[u1 * USTR + 4 * gc];
                }
            }
        }
        if (tid < PW) {                               // persist forward-solved rhs rows
            rhsY[k0 + tid] = Up[tid * USTR + 128];
            rhsZ[k0 + tid] = Up[tid * USTR + 129];
        }
        const bool hasmat = (8 * wid + 7) >= gclo;
        if (lane >= 4 * p + 4) {                      // rows >= k0+8
            // ---------- pass 1: row r0 ----------
            {
                const f4 la = *(const f4*)&P[r0 * PSTR];
                const f4 lb = *(const f4*)&P[r0 * PSTR + 4];
                if (hasmat) {
                    #pragma unroll
                    for (int c = 0; c < 8; ++c) {
                        const int gc = 8 * wid + c;
                        if (gc >= gclo) {
                            f4 acc = Ar0[c];
                            acc -= *(const f4*)&Up[0 * USTR + 4 * gc] * la.x;
                            acc -= *(const f4*)&Up[1 * USTR + 4 * gc] * la.y;
                            acc -= *(const f4*)&Up[2 * USTR + 4 * gc] * la.z;
                            acc -= *(const f4*)&Up[3 * USTR + 4 * gc] * la.w;
                            acc -= *(const f4*)&Up[4 * USTR + 4 * gc] * lb.x;
                            acc -= *(const f4*)&Up[5 * USTR + 4 * gc] * lb.y;
                            acc -= *(const f4*)&Up[6 * USTR + 4 * gc] * lb.z;
                            acc -= *(const f4*)&Up[7 * USTR + 4 * gc] * lb.w;
                            Ar0[c] = acc;
                        }
                    }
                }
                if (wid == 0) {
                    float yy = rhsY[r0], zz = rhsZ[r0];
                    yy -= la.x*Up[0*USTR+128] + la.y*Up[1*USTR+128]
                        + la.z*Up[2*USTR+128] + la.w*Up[3*USTR+128]
                        + lb.x*Up[4*USTR+128] + lb.y*Up[5*USTR+128]
                        + lb.z*Up[6*USTR+128] + lb.w*Up[7*USTR+128];
                    zz -= la.x*Up[0*USTR+129] + la.y*Up[1*USTR+129]
                        + la.z*Up[2*USTR+129] + la.w*Up[3*USTR+129]
                        + lb.x*Up[4*USTR+129] + lb.y*Up[5*USTR+129]
                        + lb.z*Up[6*USTR+129] + lb.w*Up[7*USTR+129];
                    rhsY[r0] = yy; rhsZ[r0] = zz;
                }
            }
            // ---------- pass 2: row r1 ----------
            {
                const f4 la = *(const f4*)&P[r1 * PSTR];
                const f4 lb = *(const f4*)&P[r1 * PSTR + 4];
                if (hasmat) {
                    #pragma unroll
                    for (int c = 0; c < 8; ++c) {
                        const int gc = 8 * wid + c;
                        if (gc >= gclo) {
                            f4 acc = Ar1[c];
                            acc -= *(const f4*)&Up[0 * USTR + 4 * gc] * la.x;
                            acc -= *(const f4*)&Up[1 * USTR + 4 * gc] * la.y;
                            acc -= *(const f4*)&Up[2 * USTR + 4 * gc] * la.z;
                            acc -= *(const f4*)&Up[3 * USTR + 4 * gc] * la.w;
                            acc -= *(const f4*)&Up[4 * USTR + 4 * gc] * lb.x;
                            acc -= *(const f4*)&Up[5 * USTR + 4 * gc] * lb.y;
                            acc -= *(const f4*)&Up[6 * USTR + 4 * gc] * lb.z;
                            acc -= *(const f4*)&Up[7 * USTR + 4 * gc] * lb.w;
                            Ar1[c] = acc;
                        }
                    }
                }
                if (wid == 0) {
                    float yy = rhsY[r1], zz = rhsZ[r1];
                    yy -= la.x*Up[0*USTR+128] + la.y*Up[1*USTR+128]
                        + la.z*Up[2*USTR+128] + la.w*Up[3*USTR+128]
                        + lb.x*Up[4*USTR+128] + lb.y*Up[5*USTR+128]
                        + lb.z*Up[6*USTR+128] + lb.w*Up[7*USTR+128];
                    zz -= la.x*Up[0*USTR+129] + la.y*Up[1*USTR+129]
                        + la.z*Up[2*USTR+129] + la.w*Up[3*USTR+129]
                        + lb.x*Up[4*USTR+129] + lb.y*Up[5*USTR+129]
                        + lb.z*Up[6*USTR+129] + lb.w*Up[7*USTR+129];
                    rhsY[r1] = yy; rhsZ[r1] = zz;
                }
            }
        }
        __syncthreads();
    }

    // ================= blocked back substitution (both RHS) =================
    for (int pb = NPAN - 1; pb >= 0; --pb) {
        const int k0 = PW * pb;
        if (tid < 2) {                                // 8x8 upper-tri solve, Y and Z
            float* rhs = tid ? rhsZ : rhsY;
            float* sx  = tid ? sxZ  : sxY;
            float x[PW];
            #pragma unroll
            for (int kk = PW - 1; kk >= 0; --kk) {
                float acc = rhs[k0 + kk];
                #pragma unroll
                for (int jj = kk + 1; jj < PW; ++jj) acc -= Ublk[pb][kk][jj] * x[jj];
                x[kk] = acc / Ublk[pb][kk][kk];
                sx[k0 + kk] = x[kk];
            }
        }
        __syncthreads();
        if (wid == (pb >> 2) && lane < 4 * pb) {      // rank-8 back-update, row passes
            {
                f4 a0, a1;
                switch (pb & 3) {
                    case 0:  a0 = Ar0[0]; a1 = Ar0[1]; break;
                    case 1:  a0 = Ar0[2]; a1 = Ar0[3]; break;
                    case 2:  a0 = Ar0[4]; a1 = Ar0[5]; break;
                    default: a0 = Ar0[6]; a1 = Ar0[7]; break;
                }
                rhsY[r0] -= a0.x*sxY[k0]   + a0.y*sxY[k0+1] + a0.z*sxY[k0+2] + a0.w*sxY[k0+3]
                          + a1.x*sxY[k0+4] + a1.y*sxY[k0+5] + a1.z*sxY[k0+6] + a1.w*sxY[k0+7];
                rhsZ[r0] -= a0.x*sxZ[k0]   + a0.y*sxZ[k0+1] + a0.z*sxZ[k0+2] + a0.w*sxZ[k0+3]
                          + a1.x*sxZ[k0+4] + a1.y*sxZ[k0+5] + a1.z*sxZ[k0+6] + a1.w*sxZ[k0+7];
            }
            {
                f4 a0, a1;
                switch (pb & 3) {
                    case 0:  a0 = Ar1[0]; a1 = Ar1[1]; break;
                    case 1:  a0 = Ar1[2]; a1 = Ar1[3]; break;
                    case 2:  a0 = Ar1[4]; a1 = Ar1[5]; break;
                    default: a0 = Ar1[6]; a1 = Ar1[7]; break;
                }
                rhsY[r1] -= a0.x*sxY[k0]   + a0.y*sxY[k0+1] + a0.z*sxY[k0+2] + a0.w*sxY[k0+3]
                          + a1.x*sxY[k0+4] + a1.y*sxY[k0+5] + a1.z*sxY[k0+6] + a1.w*sxY[k0+7];
                rhsZ[r1] -= a0.x*sxZ[k0]   + a0.y*sxZ[k0+1] + a0.z*sxZ[k0+2] + a0.w*sxZ[k0+3]
                          + a1.x*sxZ[k0+4] + a1.y*sxZ[k0+5] + a1.z*sxZ[k0+6] + a1.w*sxZ[k0+7];
            }
        }
        __syncthreads();
    }

    // ---- Schur closure: lambda = (1'y - Q)/(1'z - 1); q = y - lambda z ----
    if (wid == 0) {
        float vY = sxY[lane] + sxY[lane + 64];
        float vZ = sxZ[lane] + sxZ[lane + 64];
        #pragma unroll
        for (int off = 32; off; off >>= 1) {
            vY += __shfl_xor(vY, off);
            vZ += __shfl_xor(vZ, off);
        }
        if (lane == 0) lamS = (vY - total_charge[m]) / (vZ - 1.0f);
    }
    __syncthreads();
    if (tid < N) out[base + tid] = sxY[tid] - lamS * sxZ[tid];
}

extern "C" void kernel_launch(void* const* d_in, const int* in_sizes, int n_in,
                              void* d_out, int out_size, void* d_ws, size_t ws_size,
                              hipStream_t stream) {
    const float* eneg           = (const float*)d_in[0];
    const float* positions      = (const float*)d_in[1];
    const float* node_attrs     = (const float*)d_in[2];
    const float* hardness       = (const float*)d_in[3];
    const float* total_charge   = (const float*)d_in[4];
    // d_in[5] = batch (unused: equal-sized sorted molecules)
    const int*   atomic_numbers = (const int*)d_in[6];
    float* out = (float*)d_out;

    ceq_solve_kernel<<<NMOL, BLOCK, 0, stream>>>(
        eneg, positions, node_attrs, hardness, total_charge, atomic_numbers, out);
}